// Round 13
// baseline (53.741 us; speedup 1.0000x reference)
//
#include <hip/hip_runtime.h>

// ShiftGraph: B=8, C=16, H=W=256, d=5 (r=2), 24 shifts.
// Output (flat float32): edges (B, E, 2) then ws (B, E), E = 1557540.
// R12: R11 (pair symmetry, 12 forward shifts, write own+mirror) restructured:
//   Phase 1: branchless compute (clamped indices) -> all 208 loads pipeline.
//   Phase 2: single burst of guarded NT stores.
// b = bid&7 pins each batch's 4 MB x-slice to one XCD L2.

#define HH 256
#define WW 256
#define CC 16
#define BB 8
#define HW (HH * WW)
#define EE 1557540

__global__ __launch_bounds__(256) void shiftgraph_kernel(
    const float* __restrict__ x, float* __restrict__ out) {
    const int bid = blockIdx.x;
    const int b = bid & 7;          // batch -> XCD
    const int h = bid >> 3;         // row
    const int w = threadIdx.x;      // col

    const float* __restrict__ xb = x + (size_t)b * (CC * HW);
    const int posc = h * WW + w;

    // clamped element offsets for the 12 forward shifts, in fixed s-order:
    // (0,1),(0,2),(1,-2)..(1,2),(2,-2)..(2,2)
    int off12[12];
    {
        int s = 0;
#pragma unroll
        for (int di = 0; di <= 2; ++di) {
#pragma unroll
            for (int dj = (di == 0 ? 1 : -2); dj <= 2; ++dj) {
                int h2 = h + di; h2 = h2 > (HH - 1) ? (HH - 1) : h2;
                int w2 = w + dj; w2 = w2 < 0 ? 0 : (w2 > (WW - 1) ? (WW - 1) : w2);
                off12[s] = h2 * WW + w2;   // garbage only where store-guarded
                ++s;
            }
        }
    }

    // ---- Phase 1: branchless accumulate over channels ----
    float acc[12];
#pragma unroll
    for (int s = 0; s < 12; ++s) acc[s] = 0.0f;

    for (int c = 0; c < CC; ++c) {
        const float* __restrict__ xc = xb + c * HW;
        const float ctr = xc[posc];
#pragma unroll
        for (int s = 0; s < 12; ++s) {
            const float d = xc[off12[s]] - ctr;
            acc[s] = fmaf(d, d, acc[s]);
        }
    }

    // ---- Phase 2: store burst (own + mirror entries) ----
    float* __restrict__ edges = out;                        // (B, E, 2)
    float* __restrict__ wsp   = out + (size_t)BB * EE * 2;  // (B, E)
    const size_t bE = (size_t)b * EE;

    int s = 0;
#pragma unroll
    for (int di = 0; di <= 2; ++di) {
#pragma unroll
        for (int dj = (di == 0 ? 1 : -2); dj <= 2; ++dj, ++s) {
            const int i = di + 2, j = dj + 2;
            const int h2 = h + di;
            const int w2 = w + dj;
            if (h2 >= HH) continue;              // uniform across block
            if (w2 < 0 || w2 >= WW) continue;    // <=2 edge lanes diverge

            const float scale = sqrtf((float)(di * di + dj * dj));
            const float wsv = -acc[s] * scale;

            // compile-time prefix offsets for (i,j) and mirror (4-i,4-j)
            int offF = 0, offM = 0;
#pragma unroll
            for (int m = 0; m < 25; ++m) {
                const int mi = m / 5, mj = m % 5;
                if (mi == 2 && mj == 2) continue;
                const int cm = (HH - (mi < 2 ? 2 - mi : mi - 2)) *
                               (WW - (mj < 2 ? 2 - mj : mj - 2));
                if (m < i * 5 + j) offF += cm;
                if (m < (4 - i) * 5 + (4 - j)) offM += cm;
            }
            const int cww = WW - (dj < 0 ? -dj : dj);
            const int e1 = offF + h * cww + (w - (dj < 0 ? -dj : 0));
            const int e2 = offM + h * cww + (w + (dj < 0 ? dj : 0));
            const int posv = di * WW + dj;

            union { float f[2]; unsigned long long u; } evF, evM;
            evF.f[0] = (float)posc;          evF.f[1] = (float)(posc + posv);
            evM.f[0] = (float)(posc + posv); evM.f[1] = (float)posc;

            __builtin_nontemporal_store(
                evF.u, reinterpret_cast<unsigned long long*>(edges + (bE + e1) * 2));
            __builtin_nontemporal_store(
                evM.u, reinterpret_cast<unsigned long long*>(edges + (bE + e2) * 2));
            __builtin_nontemporal_store(wsv, wsp + bE + e1);
            __builtin_nontemporal_store(wsv, wsp + bE + e2);
        }
    }
}

extern "C" void kernel_launch(void* const* d_in, const int* in_sizes, int n_in,
                              void* d_out, int out_size, void* d_ws, size_t ws_size,
                              hipStream_t stream) {
    const float* x = (const float*)d_in[0];
    float* out = (float*)d_out;
    dim3 block(WW);            // one thread per column
    dim3 grid(HH * BB);        // one block per (row, batch)
    shiftgraph_kernel<<<grid, block, 0, stream>>>(x, out);
}

// Round 14
// 47.167 us; speedup vs baseline: 1.1394x; 1.1394x over previous
//
#include <hip/hip_runtime.h>

// ShiftGraph: B=8, C=16, H=W=256, d=5 (r=2), 24 shifts.
// Output (flat float32): edges (B, E, 2) then ws (B, E), E = 1557540.
// R14: SPLIT. Kernel A = R11 schedule (pair symmetry, per-shift guarded blocks,
// compile-time immediate addressing) writing ONLY ws. Kernel B = pure-store
// edge fill (x-independent index data, identical per batch), row-indexed grid,
// no division, constant prefix-offset table -> runs at fill rate.

#define HH 256
#define WW 256
#define CC 16
#define BB 8
#define HW (HH * WW)
#define EE 1557540

// per-shift tables in edge-list order k=0..23 (row-major (i,j), center skipped)
__constant__ int OFFT[24] = {
    0, 64516, 129286, 194310, 259080, 323596, 388366, 453391,
    518671, 583696, 648466, 713490, 778770, 844050, 909074, 973844,
    1038869, 1104149, 1169174, 1233944, 1298460, 1363230, 1428254, 1493024};
__constant__ int DIT[24] = {-2,-2,-2,-2,-2,-1,-1,-1,-1,-1, 0, 0, 0, 0, 1, 1, 1, 1, 1, 2, 2, 2, 2, 2};
__constant__ int DJT[24] = {-2,-1, 0, 1, 2,-2,-1, 0, 1, 2,-2,-1, 1, 2,-2,-1, 0, 1, 2,-2,-1, 0, 1, 2};

// ---- Kernel A: ws only (R11 structure minus edge stores) ----
__global__ __launch_bounds__(256) void ws_kernel(
    const float* __restrict__ x, float* __restrict__ out) {
    const int bid = blockIdx.x;
    const int b = bid & 7;          // batch -> XCD
    const int h = bid >> 3;         // row
    const int w = threadIdx.x;      // col

    const float* __restrict__ xb = x + (size_t)b * (CC * HW);

    float c0[CC];
#pragma unroll
    for (int c = 0; c < CC; ++c)
        c0[c] = xb[c * HW + h * WW + w];

    float* __restrict__ wsp = out + (size_t)BB * EE * 2;  // (B, E)
    const size_t bE = (size_t)b * EE;

#pragma unroll
    for (int i = 2; i < 5; ++i) {
#pragma unroll
        for (int j = (i == 2 ? 3 : 0); j < 5; ++j) {
            const int di = i - 2, dj = j - 2;
            const int h2 = h + di;
            if (h2 >= HH) continue;              // uniform across block
            const int w2 = w + dj;
            if (w2 < 0 || w2 >= WW) continue;    // <=2 edge lanes diverge

            float sum = 0.0f;
#pragma unroll
            for (int c = 0; c < CC; ++c) {
                const float d = xb[c * HW + h2 * WW + w2] - c0[c];
                sum = fmaf(d, d, sum);
            }
            const float scale = sqrtf((float)(di * di + dj * dj));
            const float wsv = -sum * scale;

            int offF = 0, offM = 0;
#pragma unroll
            for (int m = 0; m < 25; ++m) {
                const int mi = m / 5, mj = m % 5;
                if (mi == 2 && mj == 2) continue;
                const int cm = (HH - (mi < 2 ? 2 - mi : mi - 2)) *
                               (WW - (mj < 2 ? 2 - mj : mj - 2));
                if (m < i * 5 + j) offF += cm;
                if (m < (4 - i) * 5 + (4 - j)) offM += cm;
            }
            const int cww = WW - (dj < 0 ? -dj : dj);
            const int e1 = offF + h * cww + (w - (dj < 0 ? -dj : 0));
            const int e2 = offM + h * cww + (w + (dj < 0 ? dj : 0));

            __builtin_nontemporal_store(wsv, wsp + bE + e1);
            __builtin_nontemporal_store(wsv, wsp + bE + e2);
        }
    }
}

// ---- Kernel B: pure-store edge fill ----
__global__ __launch_bounds__(256) void edges_kernel(float* __restrict__ out) {
    const int s  = blockIdx.y;       // shift 0..23
    const int hh = blockIdx.x;       // row within crop
    const int di = DIT[s], dj = DJT[s];
    const int adi = di < 0 ? -di : di;
    const int adj = dj < 0 ? -dj : dj;
    const int chh = HH - adi, cww = WW - adj;
    if (hh >= chh) return;           // uniform across block
    const int ww = threadIdx.x;
    if (ww >= cww) return;           // <=2 lanes idle

    const int h0 = di < 0 ? -di : 0;
    const int w0 = dj < 0 ? -dj : 0;
    const int pos  = (h0 + hh) * WW + (w0 + ww);
    const int pos2 = pos + di * WW + dj;
    const int e = OFFT[s] + hh * cww + ww;

    const float2 ev = make_float2((float)pos, (float)pos2);
#pragma unroll
    for (int b = 0; b < BB; ++b)
        *reinterpret_cast<float2*>(out + ((size_t)b * EE + e) * 2) = ev;
}

extern "C" void kernel_launch(void* const* d_in, const int* in_sizes, int n_in,
                              void* d_out, int out_size, void* d_ws, size_t ws_size,
                              hipStream_t stream) {
    const float* x = (const float*)d_in[0];
    float* out = (float*)d_out;

    ws_kernel<<<dim3(HH * BB), dim3(WW), 0, stream>>>(x, out);
    edges_kernel<<<dim3(HH, 24), dim3(WW), 0, stream>>>(out);
}